// Round 7
// baseline (644.738 us; speedup 1.0000x reference)
//
#include <hip/hip_runtime.h>
#include <hip/hip_bf16.h>
#include <cstdint>

#define D_DIM 768
#define BM 128
#define BN 256
#define BK 64                   // K-tile = one K=64 MFMA step; 12 tiles
#define NKT (D_DIM / BK)        // 12

typedef int   intx8    __attribute__((ext_vector_type(8)));
typedef float floatx16 __attribute__((ext_vector_type(16)));

#define SCALE_ONE 0x7F7F7F7F  // E8M0 127 = 2^0 in every byte

// ---- helpers ----------------------------------------------------------------

__device__ inline void lds_load16(const void* g, void* lds) {
  __builtin_amdgcn_global_load_lds(
      (const __attribute__((address_space(1))) unsigned int*)g,
      (__attribute__((address_space(3))) unsigned int*)lds,
      16, 0, 0);
}

__device__ inline intx8 ldfrag32(const unsigned char* p) {
  intx8 r;
  *(int4*)&r       = *(const int4*)p;         // contiguous 32 B per lane
  *((int4*)&r + 1) = *(const int4*)(p + 16);
  return r;
}

// ---- kernel 1: row L2 norm + normalize + cast to fp8 e4m3 (both inputs) -----

__global__ __launch_bounds__(256) void norm_cast_kernel(
    const float* __restrict__ EX, const float* __restrict__ EY,
    unsigned int* __restrict__ XO, unsigned int* __restrict__ YO, int Nx) {
  int row = blockIdx.x * 4 + (threadIdx.x >> 6);
  int lane = threadIdx.x & 63;
  const float* X = (row < Nx) ? EX : EY;
  unsigned int* Y = (row < Nx) ? XO : YO;
  int r = (row < Nx) ? row : (row - Nx);
  const float4* xr = (const float4*)(X + (size_t)r * D_DIM);
  float4 a = xr[lane];
  float4 b = xr[lane + 64];
  float4 c = xr[lane + 128];
  float ss = a.x*a.x + a.y*a.y + a.z*a.z + a.w*a.w
           + b.x*b.x + b.y*b.y + b.z*b.z + b.w*b.w
           + c.x*c.x + c.y*c.y + c.z*c.z + c.w*c.w;
  #pragma unroll
  for (int off = 32; off > 0; off >>= 1) ss += __shfl_xor(ss, off, 64);
  float s = 1.0f / fmaxf(sqrtf(ss), 1e-8f);
  unsigned int* yr = Y + (size_t)r * (D_DIM / 4);
  int d;
  d = __builtin_amdgcn_cvt_pk_fp8_f32(a.x * s, a.y * s, 0, false);
  d = __builtin_amdgcn_cvt_pk_fp8_f32(a.z * s, a.w * s, d, true);
  yr[lane] = (unsigned int)d;
  d = __builtin_amdgcn_cvt_pk_fp8_f32(b.x * s, b.y * s, 0, false);
  d = __builtin_amdgcn_cvt_pk_fp8_f32(b.z * s, b.w * s, d, true);
  yr[lane + 64] = (unsigned int)d;
  d = __builtin_amdgcn_cvt_pk_fp8_f32(c.x * s, c.y * s, 0, false);
  d = __builtin_amdgcn_cvt_pk_fp8_f32(c.z * s, c.w * s, d, true);
  yr[lane + 128] = (unsigned int)d;
}

// ---- kernel 2: MX-fp8 MFMA GEMM (S = A . B^T) fused with per-row max --------
// Block 128x256, 4 waves (2x2), wave tile 64x128 = 2x4 of 32x32x64 mfma_scale.
// BOTH operands through LDS (R5/R6 lesson: global-direct operands spill accs
// via compiler load-hoisting). DOUBLE-buffered, BK=64, ONE barrier per K-tile:
// deposits for tile kt+1 issue first, then 12 ds_reads + 8 MFMA of tile kt,
// then the barrier — its vmcnt(0) drain finds deposits already landed (R4
// lesson: 2-barrier/tile structure exposes full deposit latency each tile).
// LDS 49 KB -> 2 blocks/CU. Layout linear 64 B rows (measured: read conflicts
// ~0; deposit conflicts fixed at 8 cyc/instr regardless of swizzle).

__global__ __launch_bounds__(256, 2) void gemm_max_kernel(
    const unsigned char* __restrict__ A,   // exn [Nx][768] fp8 row-major
    const unsigned char* __restrict__ B,   // eyn [Ny][768] fp8 row-major
    float* __restrict__ partial,           // [ncb][Nx]
    int Nx) {
  __shared__ unsigned char As[2 * BM * BK];  // 2 x 8 KB
  __shared__ unsigned char Bs[2 * BN * BK];  // 2 x 16 KB
  __shared__ float red[2][BM];

  const int tid  = threadIdx.x;
  const int wave = tid >> 6;
  const int lane = tid & 63;
  const int wm = wave >> 1;        // 0..1: row half (64 rows)
  const int wn = wave & 1;         // 0..1: col half (128 cols)
  const int l31 = lane & 31;
  const int h   = lane >> 5;

  floatx16 acc[2][4];
  #pragma unroll
  for (int mt = 0; mt < 2; ++mt)
    #pragma unroll
    for (int nt = 0; nt < 4; ++nt)
      acc[mt][nt] = (floatx16)(0.f);

  // staging: instr covers 16 rows x 64 B; lane -> row lane>>2, chunk lane&3
  const int srow = lane >> 2;
  const int schk = (lane & 3) * 16;
  const unsigned char* gA =
      A + (size_t)(blockIdx.x * BM + wave * 32 + srow) * D_DIM + schk;
  const unsigned char* gB =
      B + (size_t)(blockIdx.y * BN + wave * 64 + srow) * D_DIM + schk;
  const size_t g16 = (size_t)16 * D_DIM;
  unsigned char* lA = As + (size_t)(wave * 32) * BK;  // wave stages 32 A rows
  unsigned char* lB = Bs + (size_t)(wave * 64) * BK;  // and 64 B rows

  // fragment row bases (within buffer 0; add buffer offset per iteration)
  const unsigned char* pA0 = As + (size_t)(wm * 64 + 0  + l31) * BK + h * 32;
  const unsigned char* pA1 = As + (size_t)(wm * 64 + 32 + l31) * BK + h * 32;
  const unsigned char* pB0 = Bs + (size_t)(wn * 128 + 0  + l31) * BK + h * 32;
  const unsigned char* pB1 = Bs + (size_t)(wn * 128 + 32 + l31) * BK + h * 32;
  const unsigned char* pB2 = Bs + (size_t)(wn * 128 + 64 + l31) * BK + h * 32;
  const unsigned char* pB3 = Bs + (size_t)(wn * 128 + 96 + l31) * BK + h * 32;

  // prologue: stage tile 0 into buffer 0
  #pragma unroll
  for (int i = 0; i < 2; ++i) lds_load16(gA + i * g16, lA + i * 1024);
  #pragma unroll
  for (int i = 0; i < 4; ++i) lds_load16(gB + i * g16, lB + i * 1024);
  __syncthreads();

  #pragma unroll
  for (int kt = 0; kt < NKT; ++kt) {
    const int cur = kt & 1;
    // stage tile kt+1 into the other buffer (free: its readers finished
    // before the barrier that ended iteration kt-1)
    if (kt + 1 < NKT) {
      const int nb = cur ^ 1;
      #pragma unroll
      for (int i = 0; i < 2; ++i)
        lds_load16(gA + (kt + 1) * BK + i * g16, lA + nb * (BM * BK) + i * 1024);
      #pragma unroll
      for (int i = 0; i < 4; ++i)
        lds_load16(gB + (kt + 1) * BK + i * g16, lB + nb * (BN * BK) + i * 1024);
    }
    const int oA = cur * (BM * BK);
    const int oB = cur * (BN * BK);
    intx8 a0 = ldfrag32(pA0 + oA);
    intx8 a1 = ldfrag32(pA1 + oA);
    intx8 b;
    b = ldfrag32(pB0 + oB);
    acc[0][0] = __builtin_amdgcn_mfma_scale_f32_32x32x64_f8f6f4(
        a0, b, acc[0][0], 0, 0, 0, SCALE_ONE, 0, SCALE_ONE);
    acc[1][0] = __builtin_amdgcn_mfma_scale_f32_32x32x64_f8f6f4(
        a1, b, acc[1][0], 0, 0, 0, SCALE_ONE, 0, SCALE_ONE);
    b = ldfrag32(pB1 + oB);
    acc[0][1] = __builtin_amdgcn_mfma_scale_f32_32x32x64_f8f6f4(
        a0, b, acc[0][1], 0, 0, 0, SCALE_ONE, 0, SCALE_ONE);
    acc[1][1] = __builtin_amdgcn_mfma_scale_f32_32x32x64_f8f6f4(
        a1, b, acc[1][1], 0, 0, 0, SCALE_ONE, 0, SCALE_ONE);
    b = ldfrag32(pB2 + oB);
    acc[0][2] = __builtin_amdgcn_mfma_scale_f32_32x32x64_f8f6f4(
        a0, b, acc[0][2], 0, 0, 0, SCALE_ONE, 0, SCALE_ONE);
    acc[1][2] = __builtin_amdgcn_mfma_scale_f32_32x32x64_f8f6f4(
        a1, b, acc[1][2], 0, 0, 0, SCALE_ONE, 0, SCALE_ONE);
    b = ldfrag32(pB3 + oB);
    acc[0][3] = __builtin_amdgcn_mfma_scale_f32_32x32x64_f8f6f4(
        a0, b, acc[0][3], 0, 0, 0, SCALE_ONE, 0, SCALE_ONE);
    acc[1][3] = __builtin_amdgcn_mfma_scale_f32_32x32x64_f8f6f4(
        a1, b, acc[1][3], 0, 0, 0, SCALE_ONE, 0, SCALE_ONE);
    // single barrier per tile: lgkm drain covers this tile's reads, vmcnt
    // drain covers deposits issued ~20 instrs ago (latency mostly hidden)
    __syncthreads();
  }

  // epilogue: per-row max over this block's 256 columns.
  // C/D (32x32): col = l31 (+nt*32 + wn*128), row = (reg&3)+8*(reg>>2)+4*h (+mt*32+wm*64)
  #pragma unroll
  for (int mt = 0; mt < 2; ++mt) {
    #pragma unroll
    for (int reg = 0; reg < 16; ++reg) {
      float v = fmaxf(fmaxf(acc[mt][0][reg], acc[mt][1][reg]),
                      fmaxf(acc[mt][2][reg], acc[mt][3][reg]));
      #pragma unroll
      for (int off = 1; off < 32; off <<= 1)
        v = fmaxf(v, __shfl_xor(v, off, 64));
      if (l31 == 0) {
        int r = wm * 64 + mt * 32 + (reg & 3) + 8 * (reg >> 2) + 4 * h;
        red[wn][r] = v;
      }
    }
  }
  __syncthreads();
  if (tid < BM) {
    float m = fmaxf(red[0][tid], red[1][tid]);
    partial[(size_t)blockIdx.y * Nx + blockIdx.x * BM + tid] = m;
  }
}

// ---- kernel 3: row max over column blocks + halfnormal transform + block sum

__global__ __launch_bounds__(256) void rowmax_kernel(
    const float* __restrict__ partial, float* __restrict__ bsum, int Nx, int ncb) {
  __shared__ float sdata[4];
  int r = blockIdx.x * blockDim.x + threadIdx.x;
  float m = -1e30f;
  for (int cb = 0; cb < ncb; ++cb)
    m = fmaxf(m, partial[(size_t)cb * Nx + r]);
  float x = 1.0f - m;
  const float logc = -0.22579135264472744f;  // 0.5*log(2/pi), sigma=1
  float l = logc - 0.5f * x * x;
  float t = -__expf(l) * l;
  #pragma unroll
  for (int off = 32; off > 0; off >>= 1) t += __shfl_xor(t, off, 64);
  int wave = threadIdx.x >> 6;
  int lane = threadIdx.x & 63;
  if (lane == 0) sdata[wave] = t;
  __syncthreads();
  if (threadIdx.x == 0)
    bsum[blockIdx.x] = sdata[0] + sdata[1] + sdata[2] + sdata[3];
}

// ---- kernel 4: final sum of block partials -> out[0], out[1] ----------------

__global__ __launch_bounds__(64) void final_kernel(
    const float* __restrict__ bsum, float* __restrict__ out, int nb) {
  int lane = threadIdx.x;
  float s = (lane < nb) ? bsum[lane] : 0.f;
  #pragma unroll
  for (int off = 32; off > 0; off >>= 1) s += __shfl_xor(s, off, 64);
  if (lane == 0) { out[0] = s; out[1] = s; }
}

// ---- launch -----------------------------------------------------------------

extern "C" void kernel_launch(void* const* d_in, const int* in_sizes, int n_in,
                              void* d_out, int out_size, void* d_ws, size_t ws_size,
                              hipStream_t stream) {
  const float* ex = (const float*)d_in[0];
  const float* ey = (const float*)d_in[1];
  const int Nx = in_sizes[0] / D_DIM;   // 8192
  const int Ny = in_sizes[1] / D_DIM;   // 16384
  const int ncb = Ny / BN;              // 64

  char* ws = (char*)d_ws;
  unsigned char* exn = (unsigned char*)ws;                 // Nx*768 fp8
  unsigned char* eyn = exn + (size_t)Nx * D_DIM;           // Ny*768 fp8
  float* partial = (float*)(eyn + (size_t)Ny * D_DIM);     // ncb*Nx f32
  float* bsum    = partial + (size_t)ncb * Nx;             // 32 f32

  norm_cast_kernel<<<(Nx + Ny) / 4, 256, 0, stream>>>(
      ex, ey, (unsigned int*)exn, (unsigned int*)eyn, Nx);
  gemm_max_kernel<<<dim3(Nx / BM, Ny / BN), 256, 0, stream>>>(exn, eyn, partial, Nx);
  rowmax_kernel<<<Nx / 256, 256, 0, stream>>>(partial, bsum, Nx, ncb);
  final_kernel<<<1, 64, 0, stream>>>(bsum, (float*)d_out, Nx / 256);
}

// Round 8
// 271.295 us; speedup vs baseline: 2.3765x; 2.3765x over previous
//
#include <hip/hip_runtime.h>
#include <hip/hip_bf16.h>
#include <cstdint>

#define D_DIM 768
#define BM 128
#define BN 256
#define BK 64                   // K-tile = one K=64 MFMA step; 12 tiles

typedef int   intx8    __attribute__((ext_vector_type(8)));
typedef float floatx16 __attribute__((ext_vector_type(16)));

#define SCALE_ONE 0x7F7F7F7F  // E8M0 127 = 2^0 in every byte

// ---- helpers ----------------------------------------------------------------

__device__ inline void lds_load16(const void* g, void* lds) {
  __builtin_amdgcn_global_load_lds(
      (const __attribute__((address_space(1))) unsigned int*)g,
      (__attribute__((address_space(3))) unsigned int*)lds,
      16, 0, 0);
}

__device__ inline intx8 ldfrag32(const unsigned char* p) {
  intx8 r;
  *(int4*)&r       = *(const int4*)p;         // contiguous 32 B per lane
  *((int4*)&r + 1) = *(const int4*)(p + 16);
  return r;
}

// ---- kernel 1: row L2 norm + normalize + cast to fp8 e4m3 (both inputs) -----

__global__ __launch_bounds__(256) void norm_cast_kernel(
    const float* __restrict__ EX, const float* __restrict__ EY,
    unsigned int* __restrict__ XO, unsigned int* __restrict__ YO, int Nx) {
  int row = blockIdx.x * 4 + (threadIdx.x >> 6);
  int lane = threadIdx.x & 63;
  const float* X = (row < Nx) ? EX : EY;
  unsigned int* Y = (row < Nx) ? XO : YO;
  int r = (row < Nx) ? row : (row - Nx);
  const float4* xr = (const float4*)(X + (size_t)r * D_DIM);
  float4 a = xr[lane];
  float4 b = xr[lane + 64];
  float4 c = xr[lane + 128];
  float ss = a.x*a.x + a.y*a.y + a.z*a.z + a.w*a.w
           + b.x*b.x + b.y*b.y + b.z*b.z + b.w*b.w
           + c.x*c.x + c.y*c.y + c.z*c.z + c.w*c.w;
  #pragma unroll
  for (int off = 32; off > 0; off >>= 1) ss += __shfl_xor(ss, off, 64);
  float s = 1.0f / fmaxf(sqrtf(ss), 1e-8f);
  unsigned int* yr = Y + (size_t)r * (D_DIM / 4);
  int d;
  d = __builtin_amdgcn_cvt_pk_fp8_f32(a.x * s, a.y * s, 0, false);
  d = __builtin_amdgcn_cvt_pk_fp8_f32(a.z * s, a.w * s, d, true);
  yr[lane] = (unsigned int)d;
  d = __builtin_amdgcn_cvt_pk_fp8_f32(b.x * s, b.y * s, 0, false);
  d = __builtin_amdgcn_cvt_pk_fp8_f32(b.z * s, b.w * s, d, true);
  yr[lane + 64] = (unsigned int)d;
  d = __builtin_amdgcn_cvt_pk_fp8_f32(c.x * s, c.y * s, 0, false);
  d = __builtin_amdgcn_cvt_pk_fp8_f32(c.z * s, c.w * s, d, true);
  yr[lane + 128] = (unsigned int)d;
}

// ---- kernel 2: MX-fp8 MFMA GEMM (S = A . B^T) fused with per-row max --------
// Block 128x256, 4 waves (2x2), wave tile 64x128 = 2x4 of 32x32x64 mfma_scale.
// Double-buffered LDS, BK=64, ONE barrier per tile. Anti-spill discipline
// (R5/R6/R7 post-mortem: full unroll + early global addresses -> compiler
// hoists ~70 64-bit deposit addresses -> 1.3 GB scratch):
//   * outer loop #pragma unroll 1, two statically-paritied tile-halves per
//     body, gA/gB advanced by += 128 per body (2 live global pointers)
//   * last body over-prefetches tile 12 into the dead buffer (stays inside
//     d_ws: A overruns into eyn, B into the partial region) -> no guards
//   * frag ds_reads issued BEFORE deposits; MFMAs after; barrier last.

#define HALF_TILE(RA, RB, LA, LB, GOFF)                                        \
  {                                                                            \
    intx8 a0 = ldfrag32(RA);                                                   \
    intx8 a1 = ldfrag32(RA + 32 * BK);                                         \
    intx8 b0 = ldfrag32(RB);                                                   \
    intx8 b1 = ldfrag32(RB + 32 * BK);                                         \
    intx8 b2 = ldfrag32(RB + 64 * BK);                                         \
    intx8 b3 = ldfrag32(RB + 96 * BK);                                         \
    lds_load16(gA + (GOFF), LA);                                               \
    lds_load16(gA + (GOFF) + g16, LA + 1024);                                  \
    lds_load16(gB + (GOFF), LB);                                               \
    lds_load16(gB + (GOFF) + g16, LB + 1024);                                  \
    lds_load16(gB + (GOFF) + 2 * g16, LB + 2048);                              \
    lds_load16(gB + (GOFF) + 3 * g16, LB + 3072);                              \
    acc[0][0] = __builtin_amdgcn_mfma_scale_f32_32x32x64_f8f6f4(               \
        a0, b0, acc[0][0], 0, 0, 0, SCALE_ONE, 0, SCALE_ONE);                  \
    acc[1][0] = __builtin_amdgcn_mfma_scale_f32_32x32x64_f8f6f4(               \
        a1, b0, acc[1][0], 0, 0, 0, SCALE_ONE, 0, SCALE_ONE);                  \
    acc[0][1] = __builtin_amdgcn_mfma_scale_f32_32x32x64_f8f6f4(               \
        a0, b1, acc[0][1], 0, 0, 0, SCALE_ONE, 0, SCALE_ONE);                  \
    acc[1][1] = __builtin_amdgcn_mfma_scale_f32_32x32x64_f8f6f4(               \
        a1, b1, acc[1][1], 0, 0, 0, SCALE_ONE, 0, SCALE_ONE);                  \
    acc[0][2] = __builtin_amdgcn_mfma_scale_f32_32x32x64_f8f6f4(               \
        a0, b2, acc[0][2], 0, 0, 0, SCALE_ONE, 0, SCALE_ONE);                  \
    acc[1][2] = __builtin_amdgcn_mfma_scale_f32_32x32x64_f8f6f4(               \
        a1, b2, acc[1][2], 0, 0, 0, SCALE_ONE, 0, SCALE_ONE);                  \
    acc[0][3] = __builtin_amdgcn_mfma_scale_f32_32x32x64_f8f6f4(               \
        a0, b3, acc[0][3], 0, 0, 0, SCALE_ONE, 0, SCALE_ONE);                  \
    acc[1][3] = __builtin_amdgcn_mfma_scale_f32_32x32x64_f8f6f4(               \
        a1, b3, acc[1][3], 0, 0, 0, SCALE_ONE, 0, SCALE_ONE);                  \
    __syncthreads();                                                           \
  }

__global__ __launch_bounds__(256, 2) void gemm_max_kernel(
    const unsigned char* __restrict__ A,   // exn [Nx][768] fp8 row-major
    const unsigned char* __restrict__ B,   // eyn [Ny][768] fp8 row-major
    float* __restrict__ partial,           // [ncb][Nx]
    int Nx) {
  __shared__ unsigned char As[2 * BM * BK];  // 2 x 8 KB
  __shared__ unsigned char Bs[2 * BN * BK];  // 2 x 16 KB
  __shared__ float red[2][BM];

  const int tid  = threadIdx.x;
  const int wave = tid >> 6;
  const int lane = tid & 63;
  const int wm = wave >> 1;        // 0..1: row half (64 rows)
  const int wn = wave & 1;         // 0..1: col half (128 cols)
  const int l31 = lane & 31;
  const int h   = lane >> 5;

  floatx16 acc[2][4];
  #pragma unroll
  for (int mt = 0; mt < 2; ++mt)
    #pragma unroll
    for (int nt = 0; nt < 4; ++nt)
      acc[mt][nt] = (floatx16)(0.f);

  // staging: instr covers 16 rows x 64 B; lane -> row lane>>2, chunk lane&3
  const int srow = lane >> 2;
  const int schk = (lane & 3) * 16;
  const unsigned char* gA =
      A + (size_t)(blockIdx.x * BM + wave * 32 + srow) * D_DIM + schk;
  const unsigned char* gB =
      B + (size_t)(blockIdx.y * BN + wave * 64 + srow) * D_DIM + schk;
  const size_t g16 = (size_t)16 * D_DIM;
  unsigned char* lA0 = As + (size_t)(wave * 32) * BK;   // buf0 deposit base
  unsigned char* lA1 = lA0 + BM * BK;
  unsigned char* lB0 = Bs + (size_t)(wave * 64) * BK;
  unsigned char* lB1 = lB0 + BN * BK;

  // fragment read bases (buf0; buf1 = + BM*BK / + BN*BK)
  const unsigned char* rA = As + (size_t)(wm * 64 + l31) * BK + h * 32;
  const unsigned char* rB = Bs + (size_t)(wn * 128 + l31) * BK + h * 32;

  // prologue: stage tile 0 into buffer 0
  lds_load16(gA, lA0);
  lds_load16(gA + g16, lA0 + 1024);
  #pragma unroll
  for (int i = 0; i < 4; ++i) lds_load16(gB + i * g16, lB0 + i * 1024);
  __syncthreads();

  #pragma unroll 1
  for (int it = 0; it < 6; ++it) {
    // tile 2it: read buf0, stage tile 2it+1 -> buf1
    HALF_TILE(rA, rB, lA1, lB1, 64)
    // tile 2it+1: read buf1, stage tile 2it+2 -> buf0 (last one over-prefetches)
    HALF_TILE(rA + BM * BK, rB + BN * BK, lA0, lB0, 128)
    gA += 128;
    gB += 128;
  }

  // epilogue: per-row max over this block's 256 columns.
  // C/D (32x32): col = l31 (+nt*32 + wn*128), row = (reg&3)+8*(reg>>2)+4*h (+mt*32+wm*64)
  #pragma unroll
  for (int mt = 0; mt < 2; ++mt) {
    #pragma unroll
    for (int reg = 0; reg < 16; ++reg) {
      float v = fmaxf(fmaxf(acc[mt][0][reg], acc[mt][1][reg]),
                      fmaxf(acc[mt][2][reg], acc[mt][3][reg]));
      #pragma unroll
      for (int off = 1; off < 32; off <<= 1)
        v = fmaxf(v, __shfl_xor(v, off, 64));
      if (l31 == 0) {
        int r = wm * 64 + mt * 32 + (reg & 3) + 8 * (reg >> 2) + 4 * h;
        red[wn][r] = v;
      }
    }
  }
  __syncthreads();
  if (tid < BM) {
    float m = fmaxf(red[0][tid], red[1][tid]);
    partial[(size_t)blockIdx.y * Nx + blockIdx.x * BM + tid] = m;
  }
}

// ---- kernel 3: row max over column blocks + halfnormal transform + block sum

__global__ __launch_bounds__(256) void rowmax_kernel(
    const float* __restrict__ partial, float* __restrict__ bsum, int Nx, int ncb) {
  __shared__ float sdata[4];
  int r = blockIdx.x * blockDim.x + threadIdx.x;
  float m = -1e30f;
  for (int cb = 0; cb < ncb; ++cb)
    m = fmaxf(m, partial[(size_t)cb * Nx + r]);
  float x = 1.0f - m;
  const float logc = -0.22579135264472744f;  // 0.5*log(2/pi), sigma=1
  float l = logc - 0.5f * x * x;
  float t = -__expf(l) * l;
  #pragma unroll
  for (int off = 32; off > 0; off >>= 1) t += __shfl_xor(t, off, 64);
  int wave = threadIdx.x >> 6;
  int lane = threadIdx.x & 63;
  if (lane == 0) sdata[wave] = t;
  __syncthreads();
  if (threadIdx.x == 0)
    bsum[blockIdx.x] = sdata[0] + sdata[1] + sdata[2] + sdata[3];
}

// ---- kernel 4: final sum of block partials -> out[0], out[1] ----------------

__global__ __launch_bounds__(64) void final_kernel(
    const float* __restrict__ bsum, float* __restrict__ out, int nb) {
  int lane = threadIdx.x;
  float s = (lane < nb) ? bsum[lane] : 0.f;
  #pragma unroll
  for (int off = 32; off > 0; off >>= 1) s += __shfl_xor(s, off, 64);
  if (lane == 0) { out[0] = s; out[1] = s; }
}

// ---- launch -----------------------------------------------------------------

extern "C" void kernel_launch(void* const* d_in, const int* in_sizes, int n_in,
                              void* d_out, int out_size, void* d_ws, size_t ws_size,
                              hipStream_t stream) {
  const float* ex = (const float*)d_in[0];
  const float* ey = (const float*)d_in[1];
  const int Nx = in_sizes[0] / D_DIM;   // 8192
  const int Ny = in_sizes[1] / D_DIM;   // 16384
  const int ncb = Ny / BN;              // 64

  char* ws = (char*)d_ws;
  unsigned char* exn = (unsigned char*)ws;                 // Nx*768 fp8
  unsigned char* eyn = exn + (size_t)Nx * D_DIM;           // Ny*768 fp8
  float* partial = (float*)(eyn + (size_t)Ny * D_DIM);     // ncb*Nx f32 (also
                                                           // absorbs B over-prefetch)
  float* bsum    = partial + (size_t)ncb * Nx;             // 32 f32

  norm_cast_kernel<<<(Nx + Ny) / 4, 256, 0, stream>>>(
      ex, ey, (unsigned int*)exn, (unsigned int*)eyn, Nx);
  gemm_max_kernel<<<dim3(Nx / BM, Ny / BN), 256, 0, stream>>>(exn, eyn, partial, Nx);
  rowmax_kernel<<<Nx / 256, 256, 0, stream>>>(partial, bsum, Nx, ncb);
  final_kernel<<<1, 64, 0, stream>>>(bsum, (float*)d_out, Nx / 256);
}